// Round 5
// baseline (1546.705 us; speedup 1.0000x reference)
//
#include <hip/hip_runtime.h>
#include <hip/hip_fp16.h>
#include <math.h>

#ifndef M_PI
#define M_PI 3.14159265358979323846
#endif

// ---------------------------------------------------------------------------
// TensorNet interaction, fp32 math, fp16 LDS activations.
// Compressed irreducible rep per (n,f): u[9] =
//   { lam, a01, a02, a12, s00, s01, s02, s11, s12 }   (s22 = -s00-s11)
// Slab layout for node tensors: [9][N][F] (F contiguous).
//
// Workspace (~120.3 MB): slab A (U->T), slab B (msg->U2->V), CSR ints.
//
// Round-5 changes:
//  * weight loads vectorized to float4 (s_load_dwordx4) -> 4x fewer scalar
//    instrs/requests (scalar pipe was serializing the per-wave issue path)
//  * s_act in fp16, [edge][196] layout -> LDS 53->25.6 KB (occupancy up),
//    per-lane k-reads are __half2 pairs, message reads conflict-free
// ---------------------------------------------------------------------------

__device__ __forceinline__ float silu_f(float x) {
    return x / (1.0f + __expf(-x));
}

__device__ __forceinline__ void recon(const float u[9], float M[9]) {
    M[0] =  u[0] + u[4];
    M[1] =  u[1] + u[5];
    M[2] =  u[2] + u[6];
    M[3] = -u[1] + u[5];
    M[4] =  u[0] + u[7];
    M[5] =  u[3] + u[8];
    M[6] = -u[2] + u[6];
    M[7] = -u[3] + u[8];
    M[8] =  u[0] - u[4] - u[7];
}

// ---------------------------------------------------------------------------
// K1: per (n,f): Xn = X/(|X|^2+1), decompose -> U slabs [9][N][64]
// ---------------------------------------------------------------------------
__global__ __launch_bounds__(256) void k_node_prep(
    const float* __restrict__ X, float* __restrict__ U, int N)
{
    __shared__ float s_x[2304];
    int tid = threadIdx.x;
    size_t base = (size_t)blockIdx.x * 2304;
    size_t total = (size_t)N * 576;
    for (int idx = tid; idx < 2304; idx += 256) {
        size_t gi = base + idx;
        s_x[idx] = (gi < total) ? X[gi] : 0.f;
    }
    __syncthreads();
    int w = tid >> 6, f = tid & 63;
    int n = blockIdx.x * 4 + w;
    if (n >= N) return;
    float m[9]; float n2 = 0.f;
#pragma unroll
    for (int i = 0; i < 9; ++i) { m[i] = s_x[w * 576 + f * 9 + i]; n2 += m[i] * m[i]; }
    float inv = 1.0f / (n2 + 1.0f);
#pragma unroll
    for (int i = 0; i < 9; ++i) m[i] *= inv;
    float lam = (m[0] + m[4] + m[8]) * (1.f / 3.f);
    size_t slab = (size_t)N * 64;
    size_t t = (size_t)n * 64 + f;
    U[0 * slab + t] = lam;
    U[1 * slab + t] = 0.5f * (m[1] - m[3]);
    U[2 * slab + t] = 0.5f * (m[2] - m[6]);
    U[3 * slab + t] = 0.5f * (m[5] - m[7]);
    U[4 * slab + t] = m[0] - lam;
    U[5 * slab + t] = 0.5f * (m[1] + m[3]);
    U[6 * slab + t] = 0.5f * (m[2] + m[6]);
    U[7 * slab + t] = m[4] - lam;
    U[8 * slab + t] = 0.5f * (m[5] + m[7]);
}

// ---------------------------------------------------------------------------
// Comp GEMM (in-place safe). out[row][g] = sum_f in[row][f]*Wsel[g][f],
// row = c*N+n. Fast path: lane = row, wave = 16-col group, float4 weights
// via wave-uniform scalar loads (s_load_dwordx4).
// ---------------------------------------------------------------------------
__global__ __launch_bounds__(256) void k_comp_gemm(
    const float* in, float* out,
    const float* __restrict__ Wa, const float* __restrict__ Wb,
    const float* __restrict__ Wc, int R, int N)
{
    __shared__ float s_a[64 * 68];   // [k][row] stride 68
    int tid = threadIdx.x;
    int r0 = blockIdx.x * 64;
    for (int idx = tid; idx < 1024; idx += 256) {
        int row = idx >> 4;
        int k4 = (idx & 15) << 2;
        int gr = r0 + row;
        float4 v = make_float4(0.f, 0.f, 0.f, 0.f);
        if (gr < R) v = *(const float4*)(in + (size_t)gr * 64 + k4);
        s_a[(k4 + 0) * 68 + row] = v.x;
        s_a[(k4 + 1) * 68 + row] = v.y;
        s_a[(k4 + 2) * 68 + row] = v.z;
        s_a[(k4 + 3) * 68 + row] = v.w;
    }
    __syncthreads();

    int cA = r0 / N;
    int rlast = min(r0 + 63, R - 1);
    int cB = rlast / N;
    int gA = (cA == 0) ? 0 : (cA < 4 ? 1 : 2);
    int gB = (cB == 0) ? 0 : (cB < 4 ? 1 : 2);

    if (gA == gB) {
        // ---- fast path: lane = row, wave = col-group, float4 scalar weights
        int wv = __builtin_amdgcn_readfirstlane(tid >> 6);
        int lane = tid & 63;
        const float* W = (gA == 0) ? Wa : (gA == 1 ? Wb : Wc);
        const float4* W4 = (const float4*)W;
        float acc[16];
#pragma unroll
        for (int c = 0; c < 16; ++c) acc[c] = 0.f;
#pragma unroll 4
        for (int k4 = 0; k4 < 16; ++k4) {
            float a0 = s_a[(k4 * 4 + 0) * 68 + lane];
            float a1 = s_a[(k4 * 4 + 1) * 68 + lane];
            float a2 = s_a[(k4 * 4 + 2) * 68 + lane];
            float a3 = s_a[(k4 * 4 + 3) * 68 + lane];
#pragma unroll
            for (int c = 0; c < 16; ++c) {
                float4 w = W4[(wv * 16 + c) * 16 + k4];
                acc[c] += w.x * a0 + w.y * a1 + w.z * a2 + w.w * a3;
            }
        }
        __syncthreads();
        // bounce through LDS for coalesced stores: s_a[col][row]
#pragma unroll
        for (int c = 0; c < 16; ++c)
            s_a[(wv * 16 + c) * 68 + lane] = acc[c];
        __syncthreads();
        for (int idx = tid; idx < 1024; idx += 256) {
            int row = idx >> 4;
            int c4 = (idx & 15) << 2;
            int gr = r0 + row;
            if (gr < R) {
                float4 o = make_float4(s_a[(c4 + 0) * 68 + row],
                                       s_a[(c4 + 1) * 68 + row],
                                       s_a[(c4 + 2) * 68 + row],
                                       s_a[(c4 + 3) * 68 + row]);
                *(float4*)(out + (size_t)gr * 64 + c4) = o;
            }
        }
    } else {
        // ---- rare boundary path
        int et = tid >> 4, ct = tid & 15;
        int c0 = ct * 4;
        int rbase = r0 + et * 4;
        float4 acc[4];
#pragma unroll
        for (int cc = 0; cc < 4; ++cc) acc[cc] = make_float4(0.f, 0.f, 0.f, 0.f);
        const float* Wi[4];
#pragma unroll
        for (int i = 0; i < 4; ++i) {
            int r = min(rbase + i, R - 1);
            int c = r / N;
            int g = (c == 0) ? 0 : (c < 4 ? 1 : 2);
            Wi[i] = (g == 0) ? Wa : (g == 1 ? Wb : Wc);
        }
        for (int k = 0; k < 64; ++k) {
            float a0 = s_a[k * 68 + et * 4 + 0];
            float a1 = s_a[k * 68 + et * 4 + 1];
            float a2 = s_a[k * 68 + et * 4 + 2];
            float a3 = s_a[k * 68 + et * 4 + 3];
#pragma unroll
            for (int cc = 0; cc < 4; ++cc) {
                acc[cc].x += Wi[0][(c0 + cc) * 64 + k] * a0;
                acc[cc].y += Wi[1][(c0 + cc) * 64 + k] * a1;
                acc[cc].z += Wi[2][(c0 + cc) * 64 + k] * a2;
                acc[cc].w += Wi[3][(c0 + cc) * 64 + k] * a3;
            }
        }
        if (rbase + 0 < R) {
            float4 o = make_float4(acc[0].x, acc[1].x, acc[2].x, acc[3].x);
            *(float4*)(out + (size_t)(rbase + 0) * 64 + c0) = o;
        }
        if (rbase + 1 < R) {
            float4 o = make_float4(acc[0].y, acc[1].y, acc[2].y, acc[3].y);
            *(float4*)(out + (size_t)(rbase + 1) * 64 + c0) = o;
        }
        if (rbase + 2 < R) {
            float4 o = make_float4(acc[0].z, acc[1].z, acc[2].z, acc[3].z);
            *(float4*)(out + (size_t)(rbase + 2) * 64 + c0) = o;
        }
        if (rbase + 3 < R) {
            float4 o = make_float4(acc[0].w, acc[1].w, acc[2].w, acc[3].w);
            *(float4*)(out + (size_t)(rbase + 3) * 64 + c0) = o;
        }
    }
}

// ---------------------------------------------------------------------------
// CSR sort of edges by src: histogram -> scan -> ranked placement.
// ---------------------------------------------------------------------------
__global__ __launch_bounds__(256) void k_hist(
    const int* __restrict__ pair, int* __restrict__ count, int E)
{
    int e = blockIdx.x * 256 + threadIdx.x;
    if (e < E) atomicAdd(&count[pair[e]], 1);
}

__global__ __launch_bounds__(1024) void k_scan(
    const int* __restrict__ count, int* __restrict__ off,
    int* __restrict__ cursor, int N, int E)
{
    __shared__ int s[1024];
    __shared__ int s_carry;
    int tid = threadIdx.x;
    if (tid == 0) s_carry = 0;
    __syncthreads();
    for (int base = 0; base < N; base += 1024) {
        int i = base + tid;
        int v = (i < N) ? count[i] : 0;
        s[tid] = v;
        __syncthreads();
        for (int d = 1; d < 1024; d <<= 1) {
            int t = (tid >= d) ? s[tid - d] : 0;
            __syncthreads();
            s[tid] += t;
            __syncthreads();
        }
        int incl = s[tid];
        int excl = s_carry + incl - v;
        if (i < N) { off[i] = excl; cursor[i] = excl; }
        __syncthreads();
        if (tid == 1023) s_carry += s[1023];
        __syncthreads();
    }
    if (tid == 0) off[N] = E;
}

__global__ __launch_bounds__(256) void k_scatter_sort(
    const int* __restrict__ pair, int* __restrict__ cursor,
    int* __restrict__ eOf, int* __restrict__ dstp, int* __restrict__ srcp, int E)
{
    int e = blockIdx.x * 256 + threadIdx.x;
    if (e < E) {
        int s = pair[e];
        int d = pair[(size_t)E + e];
        int pos = atomicAdd(&cursor[s], 1);
        eOf[pos] = e;
        dstp[pos] = d;
        srcp[pos] = s;
    }
}

// ---------------------------------------------------------------------------
// K2: fused edge MLP (32->64->128->192, SiLU, x cutoff) over SORTED edge
// positions + run-accumulated message pass.
// MLP: lane = edge, wave = col-group; weights = float4 wave-uniform scalar
// loads; activations fp16 in s_act[edge][196] ([edge][col], 2-way banks).
// Final features stored at col cmp*64 + f.
// ---------------------------------------------------------------------------
__global__ __launch_bounds__(256) void k_edge_sorted(
    const float* __restrict__ radial, const float* __restrict__ d_ij,
    const int* __restrict__ eOf, const int* __restrict__ dstp,
    const int* __restrict__ srcp,
    const float* __restrict__ W1, const float* __restrict__ b1,
    const float* __restrict__ W2, const float* __restrict__ b2,
    const float* __restrict__ W3, const float* __restrict__ b3,
    const float* __restrict__ T, float* __restrict__ msg,
    int E, int N)
{
    __shared__ __half s_act[64 * 196];   // [edge][col], pad to 196
    __shared__ float s_C[64];
    __shared__ int s_e[64];
    __shared__ int s_src[64];
    __shared__ int s_dst[64];
    int tid = threadIdx.x;
    int p0 = blockIdx.x * 64;

    if (tid < 64) {
        int p = p0 + tid;
        int e = -1, s = 0, d = 0; float C = 0.f;
        if (p < E) {
            e = eOf[p];
            s = srcp[p];
            d = dstp[p];
            float dd = d_ij[e];
            C = (dd < 5.0f) ? 0.5f * (cosf((float)M_PI * dd * 0.2f) + 1.0f) : 0.0f;
        }
        s_e[tid] = e; s_src[tid] = s; s_dst[tid] = d; s_C[tid] = C;
    }
    __syncthreads();

    {   // stage rbf: s_act[j][k] = radial[eOf[p0+j]*32+k], fp16
        int j = tid >> 2;
        int kk = (tid & 3) * 8;
        int e = s_e[j];
        float4 v0 = make_float4(0.f, 0.f, 0.f, 0.f), v1 = v0;
        if (e >= 0) {
            v0 = *(const float4*)(radial + (size_t)e * 32 + kk);
            v1 = *(const float4*)(radial + (size_t)e * 32 + kk + 4);
        }
        __half2* dst = (__half2*)&s_act[j * 196 + kk];
        dst[0] = __floats2half2_rn(v0.x, v0.y);
        dst[1] = __floats2half2_rn(v0.z, v0.w);
        dst[2] = __floats2half2_rn(v1.x, v1.y);
        dst[3] = __floats2half2_rn(v1.z, v1.w);
    }
    __syncthreads();

    int wv = __builtin_amdgcn_readfirstlane(tid >> 6);
    int lane = tid & 63;
    const int arow = lane * 196;

    // ---- layer 1: 32 -> 64, wave owns cols [wv*16, wv*16+16)
    {
        const float4* W1v = (const float4*)W1;   // row = 8 float4
        float acc[16];
#pragma unroll
        for (int c = 0; c < 16; ++c) acc[c] = b1[wv * 16 + c];
#pragma unroll
        for (int k4 = 0; k4 < 8; ++k4) {
            float2 f01 = __half22float2(*(const __half2*)&s_act[arow + k4 * 4]);
            float2 f23 = __half22float2(*(const __half2*)&s_act[arow + k4 * 4 + 2]);
#pragma unroll
            for (int c = 0; c < 16; ++c) {
                float4 w = W1v[(wv * 16 + c) * 8 + k4];
                acc[c] += w.x * f01.x + w.y * f01.y + w.z * f23.x + w.w * f23.y;
            }
        }
        __syncthreads();
#pragma unroll
        for (int i = 0; i < 8; ++i)
            *(__half2*)&s_act[arow + wv * 16 + 2 * i] =
                __floats2half2_rn(silu_f(acc[2 * i]), silu_f(acc[2 * i + 1]));
        __syncthreads();
    }

    // ---- layer 2: 64 -> 128, wave owns cols [wv*32, wv*32+32)
    {
        const float4* W2v = (const float4*)W2;   // row = 16 float4
        float acc[32];
#pragma unroll
        for (int c = 0; c < 32; ++c) acc[c] = b2[wv * 32 + c];
#pragma unroll 2
        for (int k4 = 0; k4 < 16; ++k4) {
            float2 f01 = __half22float2(*(const __half2*)&s_act[arow + k4 * 4]);
            float2 f23 = __half22float2(*(const __half2*)&s_act[arow + k4 * 4 + 2]);
#pragma unroll
            for (int c = 0; c < 32; ++c) {
                float4 w = W2v[(wv * 32 + c) * 16 + k4];
                acc[c] += w.x * f01.x + w.y * f01.y + w.z * f23.x + w.w * f23.y;
            }
        }
        __syncthreads();
#pragma unroll
        for (int i = 0; i < 16; ++i)
            *(__half2*)&s_act[arow + wv * 32 + 2 * i] =
                __floats2half2_rn(silu_f(acc[2 * i]), silu_f(acc[2 * i + 1]));
        __syncthreads();
    }

    // ---- layer 3: 128 -> 192, wave owns raw cols [wv*48, wv*48+48)
    // raw col o stored at col (o%3)*64 + o/3  (= cmp*64 + f)
    {
        const float4* W3v = (const float4*)W3;   // row = 32 float4
        float acc[48];
#pragma unroll
        for (int c = 0; c < 48; ++c) acc[c] = b3[wv * 48 + c];
#pragma unroll 2
        for (int k4 = 0; k4 < 32; ++k4) {
            float2 f01 = __half22float2(*(const __half2*)&s_act[arow + k4 * 4]);
            float2 f23 = __half22float2(*(const __half2*)&s_act[arow + k4 * 4 + 2]);
#pragma unroll
            for (int c = 0; c < 48; ++c) {
                float4 w = W3v[(wv * 48 + c) * 32 + k4];
                acc[c] += w.x * f01.x + w.y * f01.y + w.z * f23.x + w.w * f23.y;
            }
        }
        __syncthreads();
        float C = s_C[lane];
        // c and c+3 share cmp g = c%3 and are adjacent in f -> pack __half2
#pragma unroll
        for (int g = 0; g < 3; ++g)
#pragma unroll
            for (int i = 0; i < 8; ++i) {
                float v0 = silu_f(acc[g + 6 * i]) * C;
                float v1 = silu_f(acc[g + 6 * i + 3]) * C;
                *(__half2*)&s_act[arow + g * 64 + wv * 16 + 2 * i] =
                    __floats2half2_rn(v0, v1);
            }
        __syncthreads();
    }

    // ---- message pass over sorted runs. wave wv -> comps, lane = f.
    {
        size_t slab = (size_t)N * 64;
        int cb = (wv < 3) ? wv * 2 : 7;        // comp base: 0,2,4,7
        int nc = (wv == 2) ? 3 : 2;            // comps per wave
        int c0 = cb, c1 = cb + 1, c2 = cb + 2; // c2 only if nc==3
        int gA = (c0 == 0) ? 0 : ((c0 < 4) ? 1 : 2);
        int gB = (c1 < 4) ? 1 : 2;
        const int offA = gA * 64 + lane;
        const int offB = gB * 64 + lane;
        const int offC = 2 * 64 + lane;

        float acc0 = 0.f, acc1 = 0.f, acc2 = 0.f;
        int cur = -1, jstart = 0;
        int jmax = min(64, E - p0);

        auto flush = [&](int jend) {
            if (cur < 0) return;
            long ps = (long)p0 + jstart;
            long pe = (long)p0 + jend;
            bool lb = (ps == 0) || (srcp[ps - 1] != cur);
            bool rb = (pe >= (long)E) || (srcp[pe] != cur);
            size_t b = (size_t)cur * 64 + lane;
            if (lb && rb) {
                msg[(size_t)c0 * slab + b] = acc0;
                msg[(size_t)c1 * slab + b] = acc1;
                if (nc == 3) msg[(size_t)c2 * slab + b] = acc2;
            } else {
                atomicAdd(&msg[(size_t)c0 * slab + b], acc0);
                atomicAdd(&msg[(size_t)c1 * slab + b], acc1);
                if (nc == 3) atomicAdd(&msg[(size_t)c2 * slab + b], acc2);
            }
            acc0 = acc1 = acc2 = 0.f;
        };

        for (int j = 0; j < jmax; ++j) {
            int s = s_src[j];
            if (s != cur) { flush(j); cur = s; jstart = j; }
            int d = s_dst[j];
            size_t bd = (size_t)d * 64 + lane;
            float rfA = __half2float(s_act[j * 196 + offA]);
            float rfB = __half2float(s_act[j * 196 + offB]);
            acc0 += rfA * T[(size_t)c0 * slab + bd];
            acc1 += rfB * T[(size_t)c1 * slab + bd];
            if (nc == 3) {
                float rfC = __half2float(s_act[j * 196 + offC]);
                acc2 += rfC * T[(size_t)c2 * slab + bd];
            }
        }
        flush(jmax);
    }
}

// ---------------------------------------------------------------------------
// K4a (in-place safe): M=recon(msg), Y=recon(T), P=scale*(MY+YM),
// decompose+normalize -> U2
// ---------------------------------------------------------------------------
__global__ __launch_bounds__(256) void k_node_mix(
    const float* msg, const float* __restrict__ T,
    const float* __restrict__ charges, float* U2, int N)
{
    int t = blockIdx.x * 256 + threadIdx.x;
    if (t >= N * 64) return;
    int n = t >> 6;
    size_t slab = (size_t)N * 64;
    float um[9], uy[9];
#pragma unroll
    for (int c = 0; c < 9; ++c) { um[c] = msg[c * slab + t]; uy[c] = T[c * slab + t]; }
    float M[9], Y[9];
    recon(um, M);
    recon(uy, Y);
    float P[9];
#pragma unroll
    for (int i = 0; i < 3; ++i)
#pragma unroll
        for (int j = 0; j < 3; ++j) {
            float s = 0.f;
#pragma unroll
            for (int k = 0; k < 3; ++k)
                s += M[i * 3 + k] * Y[k * 3 + j] + Y[i * 3 + k] * M[k * 3 + j];
            P[i * 3 + j] = s;
        }
    float sc = 1.0f + 0.1f * charges[n];
    float nrm = 0.f;
#pragma unroll
    for (int i = 0; i < 9; ++i) { P[i] *= sc; nrm += P[i] * P[i]; }
    float inv = 1.0f / (nrm + 1.0f);
    float lam = (P[0] + P[4] + P[8]) * (1.f / 3.f);
    U2[0 * slab + t] = lam * inv;
    U2[1 * slab + t] = 0.5f * (P[1] - P[3]) * inv;
    U2[2 * slab + t] = 0.5f * (P[2] - P[6]) * inv;
    U2[3 * slab + t] = 0.5f * (P[5] - P[7]) * inv;
    U2[4 * slab + t] = (P[0] - lam) * inv;
    U2[5 * slab + t] = 0.5f * (P[1] + P[3]) * inv;
    U2[6 * slab + t] = 0.5f * (P[2] + P[6]) * inv;
    U2[7 * slab + t] = (P[4] - lam) * inv;
    U2[8 * slab + t] = 0.5f * (P[5] + P[7]) * inv;
}

// ---------------------------------------------------------------------------
// Output: out = Xn + dX + scale * dX@dX   (Xn recomputed; dX = recon(V))
// ---------------------------------------------------------------------------
__global__ __launch_bounds__(256) void k_out(
    const float* __restrict__ V, const float* __restrict__ X,
    const float* __restrict__ charges, float* __restrict__ out, int N)
{
    __shared__ float s_x[2304];
    __shared__ float s_o[2304];
    int tid = threadIdx.x;
    int blk = blockIdx.x;
    size_t base = (size_t)blk * 2304;
    size_t total = (size_t)N * 576;
    for (int idx = tid; idx < 2304; idx += 256) {
        size_t gi = base + idx;
        s_x[idx] = (gi < total) ? X[gi] : 0.f;
    }
    __syncthreads();
    int t = blk * 256 + tid;
    if (t < N * 64) {
        int n = t >> 6;
        int w = tid >> 6, f = tid & 63;
        size_t slab = (size_t)N * 64;
        float m[9]; float n2 = 0.f;
#pragma unroll
        for (int i = 0; i < 9; ++i) { m[i] = s_x[w * 576 + f * 9 + i]; n2 += m[i] * m[i]; }
        float invn = 1.0f / (n2 + 1.0f);
#pragma unroll
        for (int i = 0; i < 9; ++i) m[i] *= invn;
        float uv[9];
#pragma unroll
        for (int c = 0; c < 9; ++c) uv[c] = V[c * slab + t];
        float dX[9];
        recon(uv, dX);
        float sc = 1.0f + 0.1f * charges[n];
#pragma unroll
        for (int i = 0; i < 3; ++i)
#pragma unroll
            for (int j = 0; j < 3; ++j) {
                float s = 0.f;
#pragma unroll
                for (int k = 0; k < 3; ++k) s += dX[i * 3 + k] * dX[k * 3 + j];
                s_o[w * 576 + f * 9 + i * 3 + j] = m[i * 3 + j] + dX[i * 3 + j] + sc * s;
            }
    }
    __syncthreads();
    for (int idx = tid; idx < 2304; idx += 256) {
        size_t gi = base + idx;
        if (gi < total) out[gi] = s_o[idx];
    }
}

// ---------------------------------------------------------------------------
extern "C" void kernel_launch(void* const* d_in, const int* in_sizes, int n_in,
                              void* d_out, int out_size, void* d_ws, size_t ws_size,
                              hipStream_t stream)
{
    const float* X       = (const float*)d_in[0];
    const int*   pair    = (const int*)d_in[1];
    const float* dij     = (const float*)d_in[2];
    const float* radial  = (const float*)d_in[3];
    const float* charges = (const float*)d_in[4];
    const float* W1  = (const float*)d_in[5];
    const float* b1  = (const float*)d_in[6];
    const float* W2  = (const float*)d_in[7];
    const float* b2  = (const float*)d_in[8];
    const float* W3  = (const float*)d_in[9];
    const float* b3  = (const float*)d_in[10];
    const float* Wl0 = (const float*)d_in[11];
    const float* Wl1 = (const float*)d_in[12];
    const float* Wl2 = (const float*)d_in[13];
    const float* Wl3 = (const float*)d_in[14];
    const float* Wl4 = (const float*)d_in[15];
    const float* Wl5 = (const float*)d_in[16];

    int N = in_sizes[4];
    int E = in_sizes[2];
    int R = 9 * N;
    int nb_gemm = (R + 63) / 64;
    int nb_node4 = (N + 3) / 4;
    int nb_edge = (E + 63) / 64;
    size_t slab9 = (size_t)N * 64 * 9;

    float* A = (float*)d_ws;        // U -> T (in-place GEMM)
    float* B = A + slab9;           // msg -> U2 -> V (in-place chain)
    int* ints   = (int*)(B + slab9);
    int* count  = ints;
    int* off    = count + N;
    int* cursor = off + N + 1;
    int* eOf    = cursor + N;
    int* dstp   = eOf + E;
    int* srcp   = dstp + E;

    hipMemsetAsync(count, 0, (size_t)N * sizeof(int), stream);
    hipMemsetAsync(B, 0, slab9 * sizeof(float), stream);

    k_node_prep<<<nb_node4, 256, 0, stream>>>(X, A, N);
    k_comp_gemm<<<nb_gemm, 256, 0, stream>>>(A, A, Wl0, Wl1, Wl2, R, N);

    k_hist<<<(E + 255) / 256, 256, 0, stream>>>(pair, count, E);
    k_scan<<<1, 1024, 0, stream>>>(count, off, cursor, N, E);
    k_scatter_sort<<<(E + 255) / 256, 256, 0, stream>>>(pair, cursor, eOf, dstp, srcp, E);

    k_edge_sorted<<<nb_edge, 256, 0, stream>>>(radial, dij, eOf, dstp, srcp,
                                               W1, b1, W2, b2, W3, b3, A, B, E, N);

    k_node_mix<<<(N * 64 + 255) / 256, 256, 0, stream>>>(B, A, charges, B, N);
    k_comp_gemm<<<nb_gemm, 256, 0, stream>>>(B, B, Wl3, Wl4, Wl5, R, N);
    k_out<<<(N * 64 + 255) / 256, 256, 0, stream>>>(B, X, charges, (float*)d_out, N);
}

// Round 6
// 632.062 us; speedup vs baseline: 2.4471x; 2.4471x over previous
//
#include <hip/hip_runtime.h>
#include <hip/hip_fp16.h>
#include <math.h>

#ifndef M_PI
#define M_PI 3.14159265358979323846
#endif

// ---------------------------------------------------------------------------
// TensorNet interaction. fp32 math, fp16 LDS activations, MFMA fp16 MLP.
// Compressed irreducible rep per (n,f): u[9] =
//   { lam, a01, a02, a12, s00, s01, s02, s11, s12 }   (s22 = -s00-s11)
// Slab layout for node tensors: [9][N][F] (F contiguous).
//
// Workspace: slab A (U->T), slab B (msg->U2->V), Wf (fp16 MFMA fragments,
// 69.6 KB), CSR ints.
//
// Round-6 changes:
//  * edge MLP runs on MFMA (mfma_f32_16x16x32_f16): weights pre-converted
//    once to fragment-ready fp16 (k_wcvt); per wave 68 MFMAs replace ~8.7K
//    VALU FMAs. A-frags = ds_read_b128 from fp16 LDS rows padded to 216.
//  * comp_gemm reverted to round-4 scalar single-dword weight loads (the
//    float4 SMEM variant blew SGPR budget and demoted to VMEM: -18%).
// ---------------------------------------------------------------------------

typedef _Float16 f16x8 __attribute__((ext_vector_type(8)));
typedef float f32x4 __attribute__((ext_vector_type(4)));

#define AROW 216   // halfs per activation row (432 B = 27*16: aligned, odd*16)

__device__ __forceinline__ float silu_f(float x) {
    return x / (1.0f + __expf(-x));
}

__device__ __forceinline__ void recon(const float u[9], float M[9]) {
    M[0] =  u[0] + u[4];
    M[1] =  u[1] + u[5];
    M[2] =  u[2] + u[6];
    M[3] = -u[1] + u[5];
    M[4] =  u[0] + u[7];
    M[5] =  u[3] + u[8];
    M[6] = -u[2] + u[6];
    M[7] = -u[3] + u[8];
    M[8] =  u[0] - u[4] - u[7];
}

// ---------------------------------------------------------------------------
// K1: per (n,f): Xn = X/(|X|^2+1), decompose -> U slabs [9][N][64]
// ---------------------------------------------------------------------------
__global__ __launch_bounds__(256) void k_node_prep(
    const float* __restrict__ X, float* __restrict__ U, int N)
{
    __shared__ float s_x[2304];
    int tid = threadIdx.x;
    size_t base = (size_t)blockIdx.x * 2304;
    size_t total = (size_t)N * 576;
    for (int idx = tid; idx < 2304; idx += 256) {
        size_t gi = base + idx;
        s_x[idx] = (gi < total) ? X[gi] : 0.f;
    }
    __syncthreads();
    int w = tid >> 6, f = tid & 63;
    int n = blockIdx.x * 4 + w;
    if (n >= N) return;
    float m[9]; float n2 = 0.f;
#pragma unroll
    for (int i = 0; i < 9; ++i) { m[i] = s_x[w * 576 + f * 9 + i]; n2 += m[i] * m[i]; }
    float inv = 1.0f / (n2 + 1.0f);
#pragma unroll
    for (int i = 0; i < 9; ++i) m[i] *= inv;
    float lam = (m[0] + m[4] + m[8]) * (1.f / 3.f);
    size_t slab = (size_t)N * 64;
    size_t t = (size_t)n * 64 + f;
    U[0 * slab + t] = lam;
    U[1 * slab + t] = 0.5f * (m[1] - m[3]);
    U[2 * slab + t] = 0.5f * (m[2] - m[6]);
    U[3 * slab + t] = 0.5f * (m[5] - m[7]);
    U[4 * slab + t] = m[0] - lam;
    U[5 * slab + t] = 0.5f * (m[1] + m[3]);
    U[6 * slab + t] = 0.5f * (m[2] + m[6]);
    U[7 * slab + t] = m[4] - lam;
    U[8 * slab + t] = 0.5f * (m[5] + m[7]);
}

// ---------------------------------------------------------------------------
// Comp GEMM (round-4 form: scalar 1-dword weight loads; in-place safe).
// out[row][g] = sum_f in[row][f]*Wsel[g][f], row = c*N+n.
// ---------------------------------------------------------------------------
__global__ __launch_bounds__(256) void k_comp_gemm(
    const float* in, float* out,
    const float* __restrict__ Wa, const float* __restrict__ Wb,
    const float* __restrict__ Wc, int R, int N)
{
    __shared__ float s_a[64 * 68];   // [k][row] stride 68
    int tid = threadIdx.x;
    int r0 = blockIdx.x * 64;
    for (int idx = tid; idx < 1024; idx += 256) {
        int row = idx >> 4;
        int k4 = (idx & 15) << 2;
        int gr = r0 + row;
        float4 v = make_float4(0.f, 0.f, 0.f, 0.f);
        if (gr < R) v = *(const float4*)(in + (size_t)gr * 64 + k4);
        s_a[(k4 + 0) * 68 + row] = v.x;
        s_a[(k4 + 1) * 68 + row] = v.y;
        s_a[(k4 + 2) * 68 + row] = v.z;
        s_a[(k4 + 3) * 68 + row] = v.w;
    }
    __syncthreads();

    int cA = r0 / N;
    int rlast = min(r0 + 63, R - 1);
    int cB = rlast / N;
    int gA = (cA == 0) ? 0 : (cA < 4 ? 1 : 2);
    int gB = (cB == 0) ? 0 : (cB < 4 ? 1 : 2);

    if (gA == gB) {
        // fast path: lane = row, wave = 16-col group, scalar weights
        int wv = __builtin_amdgcn_readfirstlane(tid >> 6);
        int lane = tid & 63;
        const float* W = (gA == 0) ? Wa : (gA == 1 ? Wb : Wc);
        float acc[16];
#pragma unroll
        for (int c = 0; c < 16; ++c) acc[c] = 0.f;
#pragma unroll 4
        for (int k = 0; k < 64; ++k) {
            float a = s_a[k * 68 + lane];
#pragma unroll
            for (int c = 0; c < 16; ++c)
                acc[c] += W[(wv * 16 + c) * 64 + k] * a;
        }
        __syncthreads();
#pragma unroll
        for (int c = 0; c < 16; ++c)
            s_a[(wv * 16 + c) * 68 + lane] = acc[c];
        __syncthreads();
        for (int idx = tid; idx < 1024; idx += 256) {
            int row = idx >> 4;
            int c4 = (idx & 15) << 2;
            int gr = r0 + row;
            if (gr < R) {
                float4 o = make_float4(s_a[(c4 + 0) * 68 + row],
                                       s_a[(c4 + 1) * 68 + row],
                                       s_a[(c4 + 2) * 68 + row],
                                       s_a[(c4 + 3) * 68 + row]);
                *(float4*)(out + (size_t)gr * 64 + c4) = o;
            }
        }
    } else {
        // rare boundary path
        int et = tid >> 4, ct = tid & 15;
        int c0 = ct * 4;
        int rbase = r0 + et * 4;
        float4 acc[4];
#pragma unroll
        for (int cc = 0; cc < 4; ++cc) acc[cc] = make_float4(0.f, 0.f, 0.f, 0.f);
        const float* Wi[4];
#pragma unroll
        for (int i = 0; i < 4; ++i) {
            int r = min(rbase + i, R - 1);
            int c = r / N;
            int g = (c == 0) ? 0 : (c < 4 ? 1 : 2);
            Wi[i] = (g == 0) ? Wa : (g == 1 ? Wb : Wc);
        }
        for (int k = 0; k < 64; ++k) {
            float a0 = s_a[k * 68 + et * 4 + 0];
            float a1 = s_a[k * 68 + et * 4 + 1];
            float a2 = s_a[k * 68 + et * 4 + 2];
            float a3 = s_a[k * 68 + et * 4 + 3];
#pragma unroll
            for (int cc = 0; cc < 4; ++cc) {
                acc[cc].x += Wi[0][(c0 + cc) * 64 + k] * a0;
                acc[cc].y += Wi[1][(c0 + cc) * 64 + k] * a1;
                acc[cc].z += Wi[2][(c0 + cc) * 64 + k] * a2;
                acc[cc].w += Wi[3][(c0 + cc) * 64 + k] * a3;
            }
        }
        if (rbase + 0 < R) {
            float4 o = make_float4(acc[0].x, acc[1].x, acc[2].x, acc[3].x);
            *(float4*)(out + (size_t)(rbase + 0) * 64 + c0) = o;
        }
        if (rbase + 1 < R) {
            float4 o = make_float4(acc[0].y, acc[1].y, acc[2].y, acc[3].y);
            *(float4*)(out + (size_t)(rbase + 1) * 64 + c0) = o;
        }
        if (rbase + 2 < R) {
            float4 o = make_float4(acc[0].z, acc[1].z, acc[2].z, acc[3].z);
            *(float4*)(out + (size_t)(rbase + 2) * 64 + c0) = o;
        }
        if (rbase + 3 < R) {
            float4 o = make_float4(acc[0].w, acc[1].w, acc[2].w, acc[3].w);
            *(float4*)(out + (size_t)(rbase + 3) * 64 + c0) = o;
        }
    }
}

// ---------------------------------------------------------------------------
// Weight -> fp16 MFMA-fragment conversion (once per launch, trivial cost).
// Fragment f (512 halfs): element (lane l, j) = W[ct*16+(l&15)][ks*32+(l>>4)*8+j]
// Frags: L1 ct=0..3 -> f=ct; L2 -> f=4+ct*2+ks; L3 -> f=20+ct*4+ks.
// ---------------------------------------------------------------------------
__global__ __launch_bounds__(256) void k_wcvt(
    const float* __restrict__ W1, const float* __restrict__ W2,
    const float* __restrict__ W3, __half* __restrict__ Wf)
{
    int idx = blockIdx.x * 256 + threadIdx.x;
    if (idx >= 34816) return;
    int frag = idx >> 9;
    int r = idx & 511;
    int l = r >> 3, j = r & 7;
    int l15 = l & 15, lg = l >> 4;
    float v;
    if (frag < 4) {
        int ct = frag;
        v = W1[(ct * 16 + l15) * 32 + (lg * 8 + j)];
    } else if (frag < 20) {
        int f2 = frag - 4;
        int ct = f2 >> 1, ks = f2 & 1;
        v = W2[(ct * 16 + l15) * 64 + (ks * 32 + lg * 8 + j)];
    } else {
        int f3 = frag - 20;
        int ct = f3 >> 2, ks = f3 & 3;
        v = W3[(ct * 16 + l15) * 128 + (ks * 32 + lg * 8 + j)];
    }
    Wf[idx] = __float2half(v);
}

// ---------------------------------------------------------------------------
// CSR sort of edges by src: histogram -> scan -> ranked placement.
// ---------------------------------------------------------------------------
__global__ __launch_bounds__(256) void k_hist(
    const int* __restrict__ pair, int* __restrict__ count, int E)
{
    int e = blockIdx.x * 256 + threadIdx.x;
    if (e < E) atomicAdd(&count[pair[e]], 1);
}

__global__ __launch_bounds__(1024) void k_scan(
    const int* __restrict__ count, int* __restrict__ off,
    int* __restrict__ cursor, int N, int E)
{
    __shared__ int s[1024];
    __shared__ int s_carry;
    int tid = threadIdx.x;
    if (tid == 0) s_carry = 0;
    __syncthreads();
    for (int base = 0; base < N; base += 1024) {
        int i = base + tid;
        int v = (i < N) ? count[i] : 0;
        s[tid] = v;
        __syncthreads();
        for (int d = 1; d < 1024; d <<= 1) {
            int t = (tid >= d) ? s[tid - d] : 0;
            __syncthreads();
            s[tid] += t;
            __syncthreads();
        }
        int incl = s[tid];
        int excl = s_carry + incl - v;
        if (i < N) { off[i] = excl; cursor[i] = excl; }
        __syncthreads();
        if (tid == 1023) s_carry += s[1023];
        __syncthreads();
    }
    if (tid == 0) off[N] = E;
}

__global__ __launch_bounds__(256) void k_scatter_sort(
    const int* __restrict__ pair, int* __restrict__ cursor,
    int* __restrict__ eOf, int* __restrict__ dstp, int* __restrict__ srcp, int E)
{
    int e = blockIdx.x * 256 + threadIdx.x;
    if (e < E) {
        int s = pair[e];
        int d = pair[(size_t)E + e];
        int pos = atomicAdd(&cursor[s], 1);
        eOf[pos] = e;
        dstp[pos] = d;
        srcp[pos] = s;
    }
}

// ---------------------------------------------------------------------------
// K2: fused edge MLP on MFMA + run-accumulated message pass.
// 64 sorted edge positions / block, 4 waves; wave w owns edge rows
// [w*16, w*16+16). Activations fp16 in s_act[edge][AROW]. A-frag = one
// ds_read_b128; B-frags = coalesced global f16x8 from Wf. C/D layout:
// col = lane&15, row = (lane>>4)*4 + reg  [HW-verified].
// ---------------------------------------------------------------------------
__global__ __launch_bounds__(256) void k_edge_sorted(
    const float* __restrict__ radial, const float* __restrict__ d_ij,
    const int* __restrict__ eOf, const int* __restrict__ dstp,
    const int* __restrict__ srcp,
    const __half* __restrict__ Wf,
    const float* __restrict__ b1, const float* __restrict__ b2,
    const float* __restrict__ b3,
    const float* __restrict__ T, float* __restrict__ msg,
    int E, int N)
{
    __shared__ __half s_act[64 * AROW];
    __shared__ float s_C[64];
    __shared__ int s_e[64];
    __shared__ int s_src[64];
    __shared__ int s_dst[64];
    int tid = threadIdx.x;
    int p0 = blockIdx.x * 64;

    if (tid < 64) {
        int p = p0 + tid;
        int e = -1, s = 0, d = 0; float C = 0.f;
        if (p < E) {
            e = eOf[p];
            s = srcp[p];
            d = dstp[p];
            float dd = d_ij[e];
            C = (dd < 5.0f) ? 0.5f * (cosf((float)M_PI * dd * 0.2f) + 1.0f) : 0.0f;
        }
        s_e[tid] = e; s_src[tid] = s; s_dst[tid] = d; s_C[tid] = C;
    }
    __syncthreads();

    {   // stage rbf: s_act[j][k], fp16 (thread tid -> row tid>>2, k (tid&3)*8)
        int j = tid >> 2;
        int kk = (tid & 3) * 8;
        int e = s_e[j];
        float4 v0 = make_float4(0.f, 0.f, 0.f, 0.f), v1 = v0;
        if (e >= 0) {
            v0 = *(const float4*)(radial + (size_t)e * 32 + kk);
            v1 = *(const float4*)(radial + (size_t)e * 32 + kk + 4);
        }
        __half2* dst = (__half2*)&s_act[j * AROW + kk];
        dst[0] = __floats2half2_rn(v0.x, v0.y);
        dst[1] = __floats2half2_rn(v0.z, v0.w);
        dst[2] = __floats2half2_rn(v1.x, v1.y);
        dst[3] = __floats2half2_rn(v1.z, v1.w);
    }
    __syncthreads();

    int w = tid >> 6;
    int lane = tid & 63;
    int l15 = lane & 15, lg = lane >> 4;
    const int row0 = w * 16;                 // this wave's edge-row base
    const int arow = (row0 + l15) * AROW;    // A-frag row base (halfs)
    const int orow = (row0 + lg * 4) * AROW; // C-write row base (reg r adds r*AROW)
    const f16x8* WF = (const f16x8*)Wf;      // WF[frag*64 + lane]
    const f32x4 zacc = {0.f, 0.f, 0.f, 0.f};

    // ---- layer 1: 32 -> 64  (K=32: one A-frag; 4 col-tiles)
    {
        f16x8 a = *(const f16x8*)&s_act[arow + lg * 8];
        f32x4 acc[4];
#pragma unroll
        for (int ct = 0; ct < 4; ++ct)
            acc[ct] = __builtin_amdgcn_mfma_f32_16x16x32_f16(a, WF[ct * 64 + lane], zacc, 0, 0, 0);
        __syncthreads();
#pragma unroll
        for (int ct = 0; ct < 4; ++ct) {
            int o = ct * 16 + l15;
            float bias = b1[o];
#pragma unroll
            for (int r = 0; r < 4; ++r)
                s_act[orow + r * AROW + o] = __float2half(silu_f(acc[ct][r] + bias));
        }
        __syncthreads();
    }

    // ---- layer 2: 64 -> 128  (K=64: 2 k-steps; 8 col-tiles)
    {
        f16x8 a0 = *(const f16x8*)&s_act[arow + 0 * 32 + lg * 8];
        f16x8 a1 = *(const f16x8*)&s_act[arow + 1 * 32 + lg * 8];
        f32x4 acc[8];
#pragma unroll
        for (int ct = 0; ct < 8; ++ct) {
            acc[ct] = __builtin_amdgcn_mfma_f32_16x16x32_f16(a0, WF[(4 + ct * 2 + 0) * 64 + lane], zacc, 0, 0, 0);
            acc[ct] = __builtin_amdgcn_mfma_f32_16x16x32_f16(a1, WF[(4 + ct * 2 + 1) * 64 + lane], acc[ct], 0, 0, 0);
        }
        __syncthreads();
#pragma unroll
        for (int ct = 0; ct < 8; ++ct) {
            int o = ct * 16 + l15;
            float bias = b2[o];
#pragma unroll
            for (int r = 0; r < 4; ++r)
                s_act[orow + r * AROW + o] = __float2half(silu_f(acc[ct][r] + bias));
        }
        __syncthreads();
    }

    // ---- layer 3: 128 -> 192  (K=128: 4 k-steps; 12 col-tiles)
    // raw col o -> stored at col (o%3)*64 + o/3  (= cmp*64 + f)
    {
        f16x8 a[4];
#pragma unroll
        for (int ks = 0; ks < 4; ++ks)
            a[ks] = *(const f16x8*)&s_act[arow + ks * 32 + lg * 8];
        float Cr[4];
#pragma unroll
        for (int r = 0; r < 4; ++r) Cr[r] = s_C[row0 + lg * 4 + r];
        __syncthreads();
#pragma unroll
        for (int ct = 0; ct < 12; ++ct) {
            f32x4 acc = zacc;
#pragma unroll
            for (int ks = 0; ks < 4; ++ks)
                acc = __builtin_amdgcn_mfma_f32_16x16x32_f16(a[ks], WF[(20 + ct * 4 + ks) * 64 + lane], acc, 0, 0, 0);
            int o = ct * 16 + l15;
            float bias = b3[o];
            int f = o / 3;
            int cmp = o - f * 3;
            int col = cmp * 64 + f;
#pragma unroll
            for (int r = 0; r < 4; ++r)
                s_act[orow + r * AROW + col] = __float2half(silu_f(acc[r] + bias) * Cr[r]);
        }
        __syncthreads();
    }

    // ---- message pass over sorted runs. wave w -> comps, lane = f.
    {
        int wv = __builtin_amdgcn_readfirstlane(w);
        size_t slab = (size_t)N * 64;
        int cb = (wv < 3) ? wv * 2 : 7;        // comp base: 0,2,4,7
        int nc = (wv == 2) ? 3 : 2;            // comps per wave
        int c0 = cb, c1 = cb + 1, c2 = cb + 2; // c2 only if nc==3
        int gA = (c0 == 0) ? 0 : ((c0 < 4) ? 1 : 2);
        int gB = (c1 < 4) ? 1 : 2;
        const int offA = gA * 64 + lane;
        const int offB = gB * 64 + lane;
        const int offC = 2 * 64 + lane;

        float acc0 = 0.f, acc1 = 0.f, acc2 = 0.f;
        int cur = -1, jstart = 0;
        int jmax = min(64, E - p0);

        auto flush = [&](int jend) {
            if (cur < 0) return;
            long ps = (long)p0 + jstart;
            long pe = (long)p0 + jend;
            bool lb = (ps == 0) || (srcp[ps - 1] != cur);
            bool rb = (pe >= (long)E) || (srcp[pe] != cur);
            size_t b = (size_t)cur * 64 + lane;
            if (lb && rb) {
                msg[(size_t)c0 * slab + b] = acc0;
                msg[(size_t)c1 * slab + b] = acc1;
                if (nc == 3) msg[(size_t)c2 * slab + b] = acc2;
            } else {
                atomicAdd(&msg[(size_t)c0 * slab + b], acc0);
                atomicAdd(&msg[(size_t)c1 * slab + b], acc1);
                if (nc == 3) atomicAdd(&msg[(size_t)c2 * slab + b], acc2);
            }
            acc0 = acc1 = acc2 = 0.f;
        };

        for (int j = 0; j < jmax; ++j) {
            int s = s_src[j];
            if (s != cur) { flush(j); cur = s; jstart = j; }
            int d = s_dst[j];
            size_t bd = (size_t)d * 64 + lane;
            float rfA = __half2float(s_act[j * AROW + offA]);
            float rfB = __half2float(s_act[j * AROW + offB]);
            acc0 += rfA * T[(size_t)c0 * slab + bd];
            acc1 += rfB * T[(size_t)c1 * slab + bd];
            if (nc == 3) {
                float rfC = __half2float(s_act[j * AROW + offC]);
                acc2 += rfC * T[(size_t)c2 * slab + bd];
            }
        }
        flush(jmax);
    }
}

// ---------------------------------------------------------------------------
// K4a (in-place safe): M=recon(msg), Y=recon(T), P=scale*(MY+YM),
// decompose+normalize -> U2
// ---------------------------------------------------------------------------
__global__ __launch_bounds__(256) void k_node_mix(
    const float* msg, const float* __restrict__ T,
    const float* __restrict__ charges, float* U2, int N)
{
    int t = blockIdx.x * 256 + threadIdx.x;
    if (t >= N * 64) return;
    int n = t >> 6;
    size_t slab = (size_t)N * 64;
    float um[9], uy[9];
#pragma unroll
    for (int c = 0; c < 9; ++c) { um[c] = msg[c * slab + t]; uy[c] = T[c * slab + t]; }
    float M[9], Y[9];
    recon(um, M);
    recon(uy, Y);
    float P[9];
#pragma unroll
    for (int i = 0; i < 3; ++i)
#pragma unroll
        for (int j = 0; j < 3; ++j) {
            float s = 0.f;
#pragma unroll
            for (int k = 0; k < 3; ++k)
                s += M[i * 3 + k] * Y[k * 3 + j] + Y[i * 3 + k] * M[k * 3 + j];
            P[i * 3 + j] = s;
        }
    float sc = 1.0f + 0.1f * charges[n];
    float nrm = 0.f;
#pragma unroll
    for (int i = 0; i < 9; ++i) { P[i] *= sc; nrm += P[i] * P[i]; }
    float inv = 1.0f / (nrm + 1.0f);
    float lam = (P[0] + P[4] + P[8]) * (1.f / 3.f);
    U2[0 * slab + t] = lam * inv;
    U2[1 * slab + t] = 0.5f * (P[1] - P[3]) * inv;
    U2[2 * slab + t] = 0.5f * (P[2] - P[6]) * inv;
    U2[3 * slab + t] = 0.5f * (P[5] - P[7]) * inv;
    U2[4 * slab + t] = (P[0] - lam) * inv;
    U2[5 * slab + t] = 0.5f * (P[1] + P[3]) * inv;
    U2[6 * slab + t] = 0.5f * (P[2] + P[6]) * inv;
    U2[7 * slab + t] = (P[4] - lam) * inv;
    U2[8 * slab + t] = 0.5f * (P[5] + P[7]) * inv;
}

// ---------------------------------------------------------------------------
// Output: out = Xn + dX + scale * dX@dX   (Xn recomputed; dX = recon(V))
// ---------------------------------------------------------------------------
__global__ __launch_bounds__(256) void k_out(
    const float* __restrict__ V, const float* __restrict__ X,
    const float* __restrict__ charges, float* __restrict__ out, int N)
{
    __shared__ float s_x[2304];
    __shared__ float s_o[2304];
    int tid = threadIdx.x;
    int blk = blockIdx.x;
    size_t base = (size_t)blk * 2304;
    size_t total = (size_t)N * 576;
    for (int idx = tid; idx < 2304; idx += 256) {
        size_t gi = base + idx;
        s_x[idx] = (gi < total) ? X[gi] : 0.f;
    }
    __syncthreads();
    int t = blk * 256 + tid;
    if (t < N * 64) {
        int n = t >> 6;
        int w = tid >> 6, f = tid & 63;
        size_t slab = (size_t)N * 64;
        float m[9]; float n2 = 0.f;
#pragma unroll
        for (int i = 0; i < 9; ++i) { m[i] = s_x[w * 576 + f * 9 + i]; n2 += m[i] * m[i]; }
        float invn = 1.0f / (n2 + 1.0f);
#pragma unroll
        for (int i = 0; i < 9; ++i) m[i] *= invn;
        float uv[9];
#pragma unroll
        for (int c = 0; c < 9; ++c) uv[c] = V[c * slab + t];
        float dX[9];
        recon(uv, dX);
        float sc = 1.0f + 0.1f * charges[n];
#pragma unroll
        for (int i = 0; i < 3; ++i)
#pragma unroll
            for (int j = 0; j < 3; ++j) {
                float s = 0.f;
#pragma unroll
                for (int k = 0; k < 3; ++k) s += dX[i * 3 + k] * dX[k * 3 + j];
                s_o[w * 576 + f * 9 + i * 3 + j] = m[i * 3 + j] + dX[i * 3 + j] + sc * s;
            }
    }
    __syncthreads();
    for (int idx = tid; idx < 2304; idx += 256) {
        size_t gi = base + idx;
        if (gi < total) out[gi] = s_o[idx];
    }
}

// ---------------------------------------------------------------------------
extern "C" void kernel_launch(void* const* d_in, const int* in_sizes, int n_in,
                              void* d_out, int out_size, void* d_ws, size_t ws_size,
                              hipStream_t stream)
{
    const float* X       = (const float*)d_in[0];
    const int*   pair    = (const int*)d_in[1];
    const float* dij     = (const float*)d_in[2];
    const float* radial  = (const float*)d_in[3];
    const float* charges = (const float*)d_in[4];
    const float* W1  = (const float*)d_in[5];
    const float* b1  = (const float*)d_in[6];
    const float* W2  = (const float*)d_in[7];
    const float* b2  = (const float*)d_in[8];
    const float* W3  = (const float*)d_in[9];
    const float* b3  = (const float*)d_in[10];
    const float* Wl0 = (const float*)d_in[11];
    const float* Wl1 = (const float*)d_in[12];
    const float* Wl2 = (const float*)d_in[13];
    const float* Wl3 = (const float*)d_in[14];
    const float* Wl4 = (const float*)d_in[15];
    const float* Wl5 = (const float*)d_in[16];

    int N = in_sizes[4];
    int E = in_sizes[2];
    int R = 9 * N;
    int nb_gemm = (R + 63) / 64;
    int nb_node4 = (N + 3) / 4;
    int nb_edge = (E + 63) / 64;
    size_t slab9 = (size_t)N * 64 * 9;

    float* A = (float*)d_ws;        // U -> T (in-place GEMM)
    float* B = A + slab9;           // msg -> U2 -> V (in-place chain)
    __half* Wf = (__half*)(B + slab9);   // 34816 halfs (16B-aligned)
    int* ints   = (int*)(Wf + 34816);
    int* count  = ints;
    int* off    = count + N;
    int* cursor = off + N + 1;
    int* eOf    = cursor + N;
    int* dstp   = eOf + E;
    int* srcp   = dstp + E;

    hipMemsetAsync(count, 0, (size_t)N * sizeof(int), stream);
    hipMemsetAsync(B, 0, slab9 * sizeof(float), stream);

    k_wcvt<<<136, 256, 0, stream>>>(W1, W2, W3, Wf);
    k_node_prep<<<nb_node4, 256, 0, stream>>>(X, A, N);
    k_comp_gemm<<<nb_gemm, 256, 0, stream>>>(A, A, Wl0, Wl1, Wl2, R, N);

    k_hist<<<(E + 255) / 256, 256, 0, stream>>>(pair, count, E);
    k_scan<<<1, 1024, 0, stream>>>(count, off, cursor, N, E);
    k_scatter_sort<<<(E + 255) / 256, 256, 0, stream>>>(pair, cursor, eOf, dstp, srcp, E);

    k_edge_sorted<<<nb_edge, 256, 0, stream>>>(radial, dij, eOf, dstp, srcp,
                                               Wf, b1, b2, b3, A, B, E, N);

    k_node_mix<<<(N * 64 + 255) / 256, 256, 0, stream>>>(B, A, charges, B, N);
    k_comp_gemm<<<nb_gemm, 256, 0, stream>>>(B, B, Wl3, Wl4, Wl5, R, N);
    k_out<<<(N * 64 + 255) / 256, 256, 0, stream>>>(B, X, charges, (float*)d_out, N);
}

// Round 7
// 631.465 us; speedup vs baseline: 2.4494x; 1.0009x over previous
//
#include <hip/hip_runtime.h>
#include <hip/hip_fp16.h>
#include <math.h>

#ifndef M_PI
#define M_PI 3.14159265358979323846
#endif

// ---------------------------------------------------------------------------
// TensorNet interaction. fp32 math, fp16 LDS activations, MFMA fp16 GEMMs.
// Compressed irreducible rep per (n,f): u[9] =
//   { lam, a01, a02, a12, s00, s01, s02, s11, s12 }   (s22 = -s00-s11)
// Slab layout for node tensors: [9][N][F] (F contiguous).
//
// ws (~149 MB): A slab (U->T fp32), B slab (msg->U2->V), Tg (fp16 paired T
// for gather), Tg6, Wf (fp16 MFMA frags: MLP 68 + 6x Wl 8), CSR ints.
//
// Round-7 changes:
//  * message-pass gather reads fp16 PAIRED T (one half2 per wave per edge):
//    gather demand 922->518 MB, load instrs ~halved.
//  * comp GEMM on MFMA (fragment-fp16 Wl, fp16 staged activations) replacing
//    the scalar-load VALU loop (1024 s_loads/wave -> 8 MFMAs/wave).
// ---------------------------------------------------------------------------

typedef _Float16 f16x8 __attribute__((ext_vector_type(8)));
typedef float f32x4 __attribute__((ext_vector_type(4)));

#define AROW 216        // halfs per activation row (432 B = 27*16)
#define MLPFRAGS 34816  // 68 frags * 512 halfs
#define WLFRAG 4096     // halfs per Wl matrix (8 frags * 512)

__device__ __forceinline__ float silu_f(float x) {
    return x / (1.0f + __expf(-x));
}

__device__ __forceinline__ void recon(const float u[9], float M[9]) {
    M[0] =  u[0] + u[4];
    M[1] =  u[1] + u[5];
    M[2] =  u[2] + u[6];
    M[3] = -u[1] + u[5];
    M[4] =  u[0] + u[7];
    M[5] =  u[3] + u[8];
    M[6] = -u[2] + u[6];
    M[7] = -u[3] + u[8];
    M[8] =  u[0] - u[4] - u[7];
}

// ---------------------------------------------------------------------------
// K1: per (n,f): Xn = X/(|X|^2+1), decompose -> U slabs [9][N][64]
// ---------------------------------------------------------------------------
__global__ __launch_bounds__(256) void k_node_prep(
    const float* __restrict__ X, float* __restrict__ U, int N)
{
    __shared__ float s_x[2304];
    int tid = threadIdx.x;
    size_t base = (size_t)blockIdx.x * 2304;
    size_t total = (size_t)N * 576;
    for (int idx = tid; idx < 2304; idx += 256) {
        size_t gi = base + idx;
        s_x[idx] = (gi < total) ? X[gi] : 0.f;
    }
    __syncthreads();
    int w = tid >> 6, f = tid & 63;
    int n = blockIdx.x * 4 + w;
    if (n >= N) return;
    float m[9]; float n2 = 0.f;
#pragma unroll
    for (int i = 0; i < 9; ++i) { m[i] = s_x[w * 576 + f * 9 + i]; n2 += m[i] * m[i]; }
    float inv = 1.0f / (n2 + 1.0f);
#pragma unroll
    for (int i = 0; i < 9; ++i) m[i] *= inv;
    float lam = (m[0] + m[4] + m[8]) * (1.f / 3.f);
    size_t slab = (size_t)N * 64;
    size_t t = (size_t)n * 64 + f;
    U[0 * slab + t] = lam;
    U[1 * slab + t] = 0.5f * (m[1] - m[3]);
    U[2 * slab + t] = 0.5f * (m[2] - m[6]);
    U[3 * slab + t] = 0.5f * (m[5] - m[7]);
    U[4 * slab + t] = m[0] - lam;
    U[5 * slab + t] = 0.5f * (m[1] + m[3]);
    U[6 * slab + t] = 0.5f * (m[2] + m[6]);
    U[7 * slab + t] = m[4] - lam;
    U[8 * slab + t] = 0.5f * (m[5] + m[7]);
}

// ---------------------------------------------------------------------------
// Weight -> fp16 MFMA-fragment conversion (once per launch).
// MLP frags (idx < 34816): L1 f=ct (4); L2 f=4+ct*2+ks (16); L3 f=20+ct*4+ks.
// Wl frags (idx >= 34816): 6 matrices x 8 frags (ct*2+ks) x 512.
// Fragment element (lane l, j) = W[ct*16+(l&15)][ks*32+(l>>4)*8+j].
// ---------------------------------------------------------------------------
__global__ __launch_bounds__(256) void k_wcvt(
    const float* __restrict__ W1, const float* __restrict__ W2,
    const float* __restrict__ W3,
    const float* __restrict__ Wl0, const float* __restrict__ Wl1,
    const float* __restrict__ Wl2, const float* __restrict__ Wl3,
    const float* __restrict__ Wl4, const float* __restrict__ Wl5,
    __half* __restrict__ Wf)
{
    int idx = blockIdx.x * 256 + threadIdx.x;
    if (idx >= MLPFRAGS + 6 * WLFRAG) return;
    float v;
    if (idx < MLPFRAGS) {
        int frag = idx >> 9;
        int r = idx & 511;
        int l = r >> 3, j = r & 7;
        int l15 = l & 15, lg = l >> 4;
        if (frag < 4) {
            int ct = frag;
            v = W1[(ct * 16 + l15) * 32 + (lg * 8 + j)];
        } else if (frag < 20) {
            int f2 = frag - 4;
            int ct = f2 >> 1, ks = f2 & 1;
            v = W2[(ct * 16 + l15) * 64 + (ks * 32 + lg * 8 + j)];
        } else {
            int f3 = frag - 20;
            int ct = f3 >> 2, ks = f3 & 3;
            v = W3[(ct * 16 + l15) * 128 + (ks * 32 + lg * 8 + j)];
        }
    } else {
        int r2 = idx - MLPFRAGS;
        int wIdx = r2 >> 12;           // /4096
        int rr = r2 & 4095;
        int f = rr >> 9;               // ct*2+ks
        int ct = f >> 1, ks = f & 1;
        int elem = rr & 511;
        int l = elem >> 3, j = elem & 7;
        int l15 = l & 15, lg = l >> 4;
        const float* W = (wIdx == 0) ? Wl0 : (wIdx == 1) ? Wl1 : (wIdx == 2) ? Wl2
                       : (wIdx == 3) ? Wl3 : (wIdx == 4) ? Wl4 : Wl5;
        v = W[(ct * 16 + l15) * 64 + (ks * 32 + lg * 8 + j)];
    }
    Wf[idx] = __float2half(v);
}

// ---------------------------------------------------------------------------
// Comp GEMM on MFMA (in-place safe). out[row][g] = sum_f in[row][f]*W[g][f],
// row = c*N+n; weight set selected by block-uniform comp group.
// Wfrag = base of this launch's 3 fragment sets (g*WLFRAG each).
// Boundary blocks (cross weight-group) take the old fp32 scalar path.
// ---------------------------------------------------------------------------
__global__ __launch_bounds__(256) void k_comp_gemm_m(
    const float* in, float* out, const __half* __restrict__ Wfrag,
    const float* __restrict__ Wa, const float* __restrict__ Wb,
    const float* __restrict__ Wc, int R, int N)
{
    __shared__ float s_f[64 * 68];
    __half* s_h = (__half*)s_f;           // staged fp16 [row][72]
    int tid = threadIdx.x;
    int r0 = blockIdx.x * 64;
    int cA = r0 / N;
    int rlast = min(r0 + 63, R - 1);
    int cB = rlast / N;
    int gA = (cA == 0) ? 0 : (cA < 4 ? 1 : 2);
    int gB = (cB == 0) ? 0 : (cB < 4 ? 1 : 2);

    if (gA == gB) {
        for (int idx = tid; idx < 1024; idx += 256) {
            int row = idx >> 4;
            int k4 = (idx & 15) << 2;
            int gr = r0 + row;
            float4 v = make_float4(0.f, 0.f, 0.f, 0.f);
            if (gr < R) v = *(const float4*)(in + (size_t)gr * 64 + k4);
            __half2* dst = (__half2*)&s_h[row * 72 + k4];
            dst[0] = __floats2half2_rn(v.x, v.y);
            dst[1] = __floats2half2_rn(v.z, v.w);
        }
        __syncthreads();
        int wv = tid >> 6, lane = tid & 63;
        int l15 = lane & 15, lg = lane >> 4;
        const f16x8* WF = (const f16x8*)(Wfrag + gA * WLFRAG);
        f16x8 a0 = *(const f16x8*)&s_h[(wv * 16 + l15) * 72 + lg * 8];
        f16x8 a1 = *(const f16x8*)&s_h[(wv * 16 + l15) * 72 + 32 + lg * 8];
        const f32x4 z = {0.f, 0.f, 0.f, 0.f};
        f32x4 acc[4];
#pragma unroll
        for (int ct = 0; ct < 4; ++ct) {
            acc[ct] = __builtin_amdgcn_mfma_f32_16x16x32_f16(a0, WF[(ct * 2 + 0) * 64 + lane], z, 0, 0, 0);
            acc[ct] = __builtin_amdgcn_mfma_f32_16x16x32_f16(a1, WF[(ct * 2 + 1) * 64 + lane], acc[ct], 0, 0, 0);
        }
        __syncthreads();
        // epilogue bounce: s_f[col][row] for coalesced float4 stores
#pragma unroll
        for (int ct = 0; ct < 4; ++ct)
#pragma unroll
            for (int r = 0; r < 4; ++r)
                s_f[(ct * 16 + l15) * 68 + wv * 16 + lg * 4 + r] = acc[ct][r];
        __syncthreads();
        for (int idx = tid; idx < 1024; idx += 256) {
            int row = idx >> 4;
            int c4 = (idx & 15) << 2;
            int gr = r0 + row;
            if (gr < R) {
                float4 o = make_float4(s_f[(c4 + 0) * 68 + row],
                                       s_f[(c4 + 1) * 68 + row],
                                       s_f[(c4 + 2) * 68 + row],
                                       s_f[(c4 + 3) * 68 + row]);
                *(float4*)(out + (size_t)gr * 64 + c4) = o;
            }
        }
    } else {
        // boundary path: fp32 scalar, stage [k][row] stride 68
        for (int idx = tid; idx < 1024; idx += 256) {
            int row = idx >> 4;
            int k4 = (idx & 15) << 2;
            int gr = r0 + row;
            float4 v = make_float4(0.f, 0.f, 0.f, 0.f);
            if (gr < R) v = *(const float4*)(in + (size_t)gr * 64 + k4);
            s_f[(k4 + 0) * 68 + row] = v.x;
            s_f[(k4 + 1) * 68 + row] = v.y;
            s_f[(k4 + 2) * 68 + row] = v.z;
            s_f[(k4 + 3) * 68 + row] = v.w;
        }
        __syncthreads();
        int et = tid >> 4, ct = tid & 15;
        int c0 = ct * 4;
        int rbase = r0 + et * 4;
        float4 acc[4];
#pragma unroll
        for (int cc = 0; cc < 4; ++cc) acc[cc] = make_float4(0.f, 0.f, 0.f, 0.f);
        const float* Wi[4];
#pragma unroll
        for (int i = 0; i < 4; ++i) {
            int r = min(rbase + i, R - 1);
            int c = r / N;
            int g = (c == 0) ? 0 : (c < 4 ? 1 : 2);
            Wi[i] = (g == 0) ? Wa : (g == 1 ? Wb : Wc);
        }
        for (int k = 0; k < 64; ++k) {
            float a0 = s_f[k * 68 + et * 4 + 0];
            float a1 = s_f[k * 68 + et * 4 + 1];
            float a2 = s_f[k * 68 + et * 4 + 2];
            float a3 = s_f[k * 68 + et * 4 + 3];
#pragma unroll
            for (int cc = 0; cc < 4; ++cc) {
                acc[cc].x += Wi[0][(c0 + cc) * 64 + k] * a0;
                acc[cc].y += Wi[1][(c0 + cc) * 64 + k] * a1;
                acc[cc].z += Wi[2][(c0 + cc) * 64 + k] * a2;
                acc[cc].w += Wi[3][(c0 + cc) * 64 + k] * a3;
            }
        }
        if (rbase + 0 < R) {
            float4 o = make_float4(acc[0].x, acc[1].x, acc[2].x, acc[3].x);
            *(float4*)(out + (size_t)(rbase + 0) * 64 + c0) = o;
        }
        if (rbase + 1 < R) {
            float4 o = make_float4(acc[0].y, acc[1].y, acc[2].y, acc[3].y);
            *(float4*)(out + (size_t)(rbase + 1) * 64 + c0) = o;
        }
        if (rbase + 2 < R) {
            float4 o = make_float4(acc[0].z, acc[1].z, acc[2].z, acc[3].z);
            *(float4*)(out + (size_t)(rbase + 2) * 64 + c0) = o;
        }
        if (rbase + 3 < R) {
            float4 o = make_float4(acc[0].w, acc[1].w, acc[2].w, acc[3].w);
            *(float4*)(out + (size_t)(rbase + 3) * 64 + c0) = o;
        }
    }
}

// ---------------------------------------------------------------------------
// T -> fp16 paired gather layout: Tg[pr][n][f] = (T[pa][..], T[pa+1][..])
// for pairs (0,1),(2,3),(4,5),(7,8); Tg6[n][f] = T[6][..].
// ---------------------------------------------------------------------------
__global__ __launch_bounds__(256) void k_tcvt(
    const float* __restrict__ T, __half2* __restrict__ Tg,
    __half* __restrict__ Tg6, int N)
{
    int t = blockIdx.x * 256 + threadIdx.x;
    if (t >= N * 64) return;
    size_t slab = (size_t)N * 64;
    const int pa[4] = {0, 2, 4, 7};
#pragma unroll
    for (int pr = 0; pr < 4; ++pr) {
        float va = T[(size_t)pa[pr] * slab + t];
        float vb = T[((size_t)pa[pr] + 1) * slab + t];
        Tg[(size_t)pr * slab + t] = __floats2half2_rn(va, vb);
    }
    Tg6[t] = __float2half(T[6 * slab + t]);
}

// ---------------------------------------------------------------------------
// CSR sort of edges by src: histogram -> scan -> ranked placement.
// ---------------------------------------------------------------------------
__global__ __launch_bounds__(256) void k_hist(
    const int* __restrict__ pair, int* __restrict__ count, int E)
{
    int e = blockIdx.x * 256 + threadIdx.x;
    if (e < E) atomicAdd(&count[pair[e]], 1);
}

__global__ __launch_bounds__(1024) void k_scan(
    const int* __restrict__ count, int* __restrict__ off,
    int* __restrict__ cursor, int N, int E)
{
    __shared__ int s[1024];
    __shared__ int s_carry;
    int tid = threadIdx.x;
    if (tid == 0) s_carry = 0;
    __syncthreads();
    for (int base = 0; base < N; base += 1024) {
        int i = base + tid;
        int v = (i < N) ? count[i] : 0;
        s[tid] = v;
        __syncthreads();
        for (int d = 1; d < 1024; d <<= 1) {
            int t = (tid >= d) ? s[tid - d] : 0;
            __syncthreads();
            s[tid] += t;
            __syncthreads();
        }
        int incl = s[tid];
        int excl = s_carry + incl - v;
        if (i < N) { off[i] = excl; cursor[i] = excl; }
        __syncthreads();
        if (tid == 1023) s_carry += s[1023];
        __syncthreads();
    }
    if (tid == 0) off[N] = E;
}

__global__ __launch_bounds__(256) void k_scatter_sort(
    const int* __restrict__ pair, int* __restrict__ cursor,
    int* __restrict__ eOf, int* __restrict__ dstp, int* __restrict__ srcp, int E)
{
    int e = blockIdx.x * 256 + threadIdx.x;
    if (e < E) {
        int s = pair[e];
        int d = pair[(size_t)E + e];
        int pos = atomicAdd(&cursor[s], 1);
        eOf[pos] = e;
        dstp[pos] = d;
        srcp[pos] = s;
    }
}

// ---------------------------------------------------------------------------
// K2: fused edge MLP on MFMA + run-accumulated message pass with fp16
// paired-T gather. 64 sorted positions/block, 4 waves (wave = 16 edge rows
// for MLP; wave = comp pair for message phase).
// ---------------------------------------------------------------------------
__global__ __launch_bounds__(256) void k_edge_sorted(
    const float* __restrict__ radial, const float* __restrict__ d_ij,
    const int* __restrict__ eOf, const int* __restrict__ dstp,
    const int* __restrict__ srcp,
    const __half* __restrict__ Wf,
    const float* __restrict__ b1, const float* __restrict__ b2,
    const float* __restrict__ b3,
    const __half2* __restrict__ Tg, const __half* __restrict__ Tg6,
    float* __restrict__ msg, int E, int N)
{
    __shared__ __half s_act[64 * AROW];
    __shared__ float s_C[64];
    __shared__ int s_e[64];
    __shared__ int s_src[64];
    __shared__ int s_dst[64];
    int tid = threadIdx.x;
    int p0 = blockIdx.x * 64;

    if (tid < 64) {
        int p = p0 + tid;
        int e = -1, s = 0, d = 0; float C = 0.f;
        if (p < E) {
            e = eOf[p];
            s = srcp[p];
            d = dstp[p];
            float dd = d_ij[e];
            C = (dd < 5.0f) ? 0.5f * (cosf((float)M_PI * dd * 0.2f) + 1.0f) : 0.0f;
        }
        s_e[tid] = e; s_src[tid] = s; s_dst[tid] = d; s_C[tid] = C;
    }
    __syncthreads();

    {   // stage rbf: s_act[j][k], fp16
        int j = tid >> 2;
        int kk = (tid & 3) * 8;
        int e = s_e[j];
        float4 v0 = make_float4(0.f, 0.f, 0.f, 0.f), v1 = v0;
        if (e >= 0) {
            v0 = *(const float4*)(radial + (size_t)e * 32 + kk);
            v1 = *(const float4*)(radial + (size_t)e * 32 + kk + 4);
        }
        __half2* dst = (__half2*)&s_act[j * AROW + kk];
        dst[0] = __floats2half2_rn(v0.x, v0.y);
        dst[1] = __floats2half2_rn(v0.z, v0.w);
        dst[2] = __floats2half2_rn(v1.x, v1.y);
        dst[3] = __floats2half2_rn(v1.z, v1.w);
    }
    __syncthreads();

    int w = tid >> 6;
    int lane = tid & 63;
    int l15 = lane & 15, lg = lane >> 4;
    const int row0 = w * 16;
    const int arow = (row0 + l15) * AROW;
    const int orow = (row0 + lg * 4) * AROW;
    const f16x8* WF = (const f16x8*)Wf;
    const f32x4 zacc = {0.f, 0.f, 0.f, 0.f};

    // ---- layer 1: 32 -> 64
    {
        f16x8 a = *(const f16x8*)&s_act[arow + lg * 8];
        f32x4 acc[4];
#pragma unroll
        for (int ct = 0; ct < 4; ++ct)
            acc[ct] = __builtin_amdgcn_mfma_f32_16x16x32_f16(a, WF[ct * 64 + lane], zacc, 0, 0, 0);
        __syncthreads();
#pragma unroll
        for (int ct = 0; ct < 4; ++ct) {
            int o = ct * 16 + l15;
            float bias = b1[o];
#pragma unroll
            for (int r = 0; r < 4; ++r)
                s_act[orow + r * AROW + o] = __float2half(silu_f(acc[ct][r] + bias));
        }
        __syncthreads();
    }

    // ---- layer 2: 64 -> 128
    {
        f16x8 a0 = *(const f16x8*)&s_act[arow + 0 * 32 + lg * 8];
        f16x8 a1 = *(const f16x8*)&s_act[arow + 1 * 32 + lg * 8];
        f32x4 acc[8];
#pragma unroll
        for (int ct = 0; ct < 8; ++ct) {
            acc[ct] = __builtin_amdgcn_mfma_f32_16x16x32_f16(a0, WF[(4 + ct * 2 + 0) * 64 + lane], zacc, 0, 0, 0);
            acc[ct] = __builtin_amdgcn_mfma_f32_16x16x32_f16(a1, WF[(4 + ct * 2 + 1) * 64 + lane], acc[ct], 0, 0, 0);
        }
        __syncthreads();
#pragma unroll
        for (int ct = 0; ct < 8; ++ct) {
            int o = ct * 16 + l15;
            float bias = b2[o];
#pragma unroll
            for (int r = 0; r < 4; ++r)
                s_act[orow + r * AROW + o] = __float2half(silu_f(acc[ct][r] + bias));
        }
        __syncthreads();
    }

    // ---- layer 3: 128 -> 192 (raw col o -> stored col (o%3)*64 + o/3)
    {
        f16x8 a[4];
#pragma unroll
        for (int ks = 0; ks < 4; ++ks)
            a[ks] = *(const f16x8*)&s_act[arow + ks * 32 + lg * 8];
        float Cr[4];
#pragma unroll
        for (int r = 0; r < 4; ++r) Cr[r] = s_C[row0 + lg * 4 + r];
        __syncthreads();
#pragma unroll
        for (int ct = 0; ct < 12; ++ct) {
            f32x4 acc = zacc;
#pragma unroll
            for (int ks = 0; ks < 4; ++ks)
                acc = __builtin_amdgcn_mfma_f32_16x16x32_f16(a[ks], WF[(20 + ct * 4 + ks) * 64 + lane], acc, 0, 0, 0);
            int o = ct * 16 + l15;
            float bias = b3[o];
            int f = o / 3;
            int cmp = o - f * 3;
            int col = cmp * 64 + f;
#pragma unroll
            for (int r = 0; r < 4; ++r)
                s_act[orow + r * AROW + col] = __float2half(silu_f(acc[r] + bias) * Cr[r]);
        }
        __syncthreads();
    }

    // ---- message pass over sorted runs. wave w -> comp pair, lane = f.
    {
        int wv = __builtin_amdgcn_readfirstlane(w);
        size_t slab = (size_t)N * 64;
        int c0 = (wv < 3) ? wv * 2 : 7;
        int c1 = c0 + 1;
        int nc = (wv == 2) ? 3 : 2;            // wave2 also handles comp 6
        int gAx = (c0 == 0) ? 0 : ((c0 < 4) ? 1 : 2);
        int gBx = (c1 < 4) ? 1 : 2;
        const int offA = gAx * 64 + lane;
        const int offB = gBx * 64 + lane;
        const __half2* TgW = Tg + (size_t)wv * slab;

        float acc0 = 0.f, acc1 = 0.f, acc2 = 0.f;
        int cur = -1, jstart = 0;
        int jmax = min(64, E - p0);

        auto flush = [&](int jend) {
            if (cur < 0) return;
            long ps = (long)p0 + jstart;
            long pe = (long)p0 + jend;
            bool lb = (ps == 0) || (srcp[ps - 1] != cur);
            bool rb = (pe >= (long)E) || (srcp[pe] != cur);
            size_t b = (size_t)cur * 64 + lane;
            if (lb && rb) {
                msg[(size_t)c0 * slab + b] = acc0;
                msg[(size_t)c1 * slab + b] = acc1;
                if (nc == 3) msg[(size_t)6 * slab + b] = acc2;
            } else {
                atomicAdd(&msg[(size_t)c0 * slab + b], acc0);
                atomicAdd(&msg[(size_t)c1 * slab + b], acc1);
                if (nc == 3) atomicAdd(&msg[(size_t)6 * slab + b], acc2);
            }
            acc0 = acc1 = acc2 = 0.f;
        };

        for (int j = 0; j < jmax; ++j) {
            int s = s_src[j];
            if (s != cur) { flush(j); cur = s; jstart = j; }
            int d = s_dst[j];
            float2 tv = __half22float2(TgW[(size_t)d * 64 + lane]);
            float rfA = __half2float(s_act[j * AROW + offA]);
            float rfB = __half2float(s_act[j * AROW + offB]);
            acc0 += rfA * tv.x;
            acc1 += rfB * tv.y;
            if (nc == 3)
                acc2 += rfB * __half2float(Tg6[(size_t)d * 64 + lane]);
        }
        flush(jmax);
    }
}

// ---------------------------------------------------------------------------
// K4a (in-place safe): M=recon(msg), Y=recon(T), P=scale*(MY+YM),
// decompose+normalize -> U2
// ---------------------------------------------------------------------------
__global__ __launch_bounds__(256) void k_node_mix(
    const float* msg, const float* __restrict__ T,
    const float* __restrict__ charges, float* U2, int N)
{
    int t = blockIdx.x * 256 + threadIdx.x;
    if (t >= N * 64) return;
    int n = t >> 6;
    size_t slab = (size_t)N * 64;
    float um[9], uy[9];
#pragma unroll
    for (int c = 0; c < 9; ++c) { um[c] = msg[c * slab + t]; uy[c] = T[c * slab + t]; }
    float M[9], Y[9];
    recon(um, M);
    recon(uy, Y);
    float P[9];
#pragma unroll
    for (int i = 0; i < 3; ++i)
#pragma unroll
        for (int j = 0; j < 3; ++j) {
            float s = 0.f;
#pragma unroll
            for (int k = 0; k < 3; ++k)
                s += M[i * 3 + k] * Y[k * 3 + j] + Y[i * 3 + k] * M[k * 3 + j];
            P[i * 3 + j] = s;
        }
    float sc = 1.0f + 0.1f * charges[n];
    float nrm = 0.f;
#pragma unroll
    for (int i = 0; i < 9; ++i) { P[i] *= sc; nrm += P[i] * P[i]; }
    float inv = 1.0f / (nrm + 1.0f);
    float lam = (P[0] + P[4] + P[8]) * (1.f / 3.f);
    U2[0 * slab + t] = lam * inv;
    U2[1 * slab + t] = 0.5f * (P[1] - P[3]) * inv;
    U2[2 * slab + t] = 0.5f * (P[2] - P[6]) * inv;
    U2[3 * slab + t] = 0.5f * (P[5] - P[7]) * inv;
    U2[4 * slab + t] = (P[0] - lam) * inv;
    U2[5 * slab + t] = 0.5f * (P[1] + P[3]) * inv;
    U2[6 * slab + t] = 0.5f * (P[2] + P[6]) * inv;
    U2[7 * slab + t] = (P[4] - lam) * inv;
    U2[8 * slab + t] = 0.5f * (P[5] + P[7]) * inv;
}

// ---------------------------------------------------------------------------
// Output: out = Xn + dX + scale * dX@dX   (Xn recomputed; dX = recon(V))
// ---------------------------------------------------------------------------
__global__ __launch_bounds__(256) void k_out(
    const float* __restrict__ V, const float* __restrict__ X,
    const float* __restrict__ charges, float* __restrict__ out, int N)
{
    __shared__ float s_x[2304];
    __shared__ float s_o[2304];
    int tid = threadIdx.x;
    int blk = blockIdx.x;
    size_t base = (size_t)blk * 2304;
    size_t total = (size_t)N * 576;
    for (int idx = tid; idx < 2304; idx += 256) {
        size_t gi = base + idx;
        s_x[idx] = (gi < total) ? X[gi] : 0.f;
    }
    __syncthreads();
    int t = blk * 256 + tid;
    if (t < N * 64) {
        int n = t >> 6;
        int w = tid >> 6, f = tid & 63;
        size_t slab = (size_t)N * 64;
        float m[9]; float n2 = 0.f;
#pragma unroll
        for (int i = 0; i < 9; ++i) { m[i] = s_x[w * 576 + f * 9 + i]; n2 += m[i] * m[i]; }
        float invn = 1.0f / (n2 + 1.0f);
#pragma unroll
        for (int i = 0; i < 9; ++i) m[i] *= invn;
        float uv[9];
#pragma unroll
        for (int c = 0; c < 9; ++c) uv[c] = V[c * slab + t];
        float dX[9];
        recon(uv, dX);
        float sc = 1.0f + 0.1f * charges[n];
#pragma unroll
        for (int i = 0; i < 3; ++i)
#pragma unroll
            for (int j = 0; j < 3; ++j) {
                float s = 0.f;
#pragma unroll
                for (int k = 0; k < 3; ++k) s += dX[i * 3 + k] * dX[k * 3 + j];
                s_o[w * 576 + f * 9 + i * 3 + j] = m[i * 3 + j] + dX[i * 3 + j] + sc * s;
            }
    }
    __syncthreads();
    for (int idx = tid; idx < 2304; idx += 256) {
        size_t gi = base + idx;
        if (gi < total) out[gi] = s_o[idx];
    }
}

// ---------------------------------------------------------------------------
extern "C" void kernel_launch(void* const* d_in, const int* in_sizes, int n_in,
                              void* d_out, int out_size, void* d_ws, size_t ws_size,
                              hipStream_t stream)
{
    const float* X       = (const float*)d_in[0];
    const int*   pair    = (const int*)d_in[1];
    const float* dij     = (const float*)d_in[2];
    const float* radial  = (const float*)d_in[3];
    const float* charges = (const float*)d_in[4];
    const float* W1  = (const float*)d_in[5];
    const float* b1  = (const float*)d_in[6];
    const float* W2  = (const float*)d_in[7];
    const float* b2  = (const float*)d_in[8];
    const float* W3  = (const float*)d_in[9];
    const float* b3  = (const float*)d_in[10];
    const float* Wl0 = (const float*)d_in[11];
    const float* Wl1 = (const float*)d_in[12];
    const float* Wl2 = (const float*)d_in[13];
    const float* Wl3 = (const float*)d_in[14];
    const float* Wl4 = (const float*)d_in[15];
    const float* Wl5 = (const float*)d_in[16];

    int N = in_sizes[4];
    int E = in_sizes[2];
    int R = 9 * N;
    int nb_gemm = (R + 63) / 64;
    int nb_node4 = (N + 3) / 4;
    int nb_edge = (E + 63) / 64;
    size_t slab = (size_t)N * 64;
    size_t slab9 = slab * 9;

    float* A = (float*)d_ws;             // U -> T (in-place GEMM)
    float* B = A + slab9;                // msg -> U2 -> V (in-place chain)
    __half2* Tg = (__half2*)(B + slab9); // 4*slab half2
    __half* Tg6 = (__half*)(Tg + 4 * slab);
    __half* Wf  = Tg6 + slab;            // 59392 halfs
    int* ints   = (int*)(Wf + MLPFRAGS + 6 * WLFRAG);
    int* count  = ints;
    int* off    = count + N;
    int* cursor = off + N + 1;
    int* eOf    = cursor + N;
    int* dstp   = eOf + E;
    int* srcp   = dstp + E;

    hipMemsetAsync(count, 0, (size_t)N * sizeof(int), stream);
    hipMemsetAsync(B, 0, slab9 * sizeof(float), stream);

    int nWf = MLPFRAGS + 6 * WLFRAG;
    k_wcvt<<<(nWf + 255) / 256, 256, 0, stream>>>(W1, W2, W3,
                                                  Wl0, Wl1, Wl2, Wl3, Wl4, Wl5, Wf);
    k_node_prep<<<nb_node4, 256, 0, stream>>>(X, A, N);
    k_comp_gemm_m<<<nb_gemm, 256, 0, stream>>>(A, A, Wf + MLPFRAGS,
                                               Wl0, Wl1, Wl2, R, N);
    k_tcvt<<<(N * 64 + 255) / 256, 256, 0, stream>>>(A, Tg, Tg6, N);

    k_hist<<<(E + 255) / 256, 256, 0, stream>>>(pair, count, E);
    k_scan<<<1, 1024, 0, stream>>>(count, off, cursor, N, E);
    k_scatter_sort<<<(E + 255) / 256, 256, 0, stream>>>(pair, cursor, eOf, dstp, srcp, E);

    k_edge_sorted<<<nb_edge, 256, 0, stream>>>(radial, dij, eOf, dstp, srcp,
                                               Wf, b1, b2, b3, Tg, Tg6, B, E, N);

    k_node_mix<<<(N * 64 + 255) / 256, 256, 0, stream>>>(B, A, charges, B, N);
    k_comp_gemm_m<<<nb_gemm, 256, 0, stream>>>(B, B, Wf + MLPFRAGS + 3 * WLFRAG,
                                               Wl3, Wl4, Wl5, R, N);
    k_out<<<(N * 64 + 255) / 256, 256, 0, stream>>>(B, X, charges, (float*)d_out, N);
}